// Round 4
// baseline (197.504 us; speedup 1.0000x reference)
//
#include <hip/hip_runtime.h>
#include <cstdint>

#define DIMD 1024
#define NROWS 8192
#define KDIM 2048   // 2*DIM

typedef unsigned short u16;
typedef __bf16 bf16x8 __attribute__((ext_vector_type(8)));
typedef float f32x4 __attribute__((ext_vector_type(4)));

__device__ __forceinline__ u16 f2bf(float f) {
  unsigned u = __builtin_bit_cast(unsigned, f);
  return (u16)((u + 0x7FFFu + ((u >> 16) & 1u)) >> 16);  // RNE
}

// Branch-free exact-enough GELU (A&S 7.1.26 erf, |err| <= 1.5e-7).
__device__ __forceinline__ float gelu_exact(float x) {
  float s = 0.70710678118654752f * x;
  float a = fabsf(s);
  float k = __fdividef(1.0f, fmaf(0.3275911f, a, 1.0f));
  float p = 1.061405429f;
  p = fmaf(p, k, -1.453152027f);
  p = fmaf(p, k, 1.421413741f);
  p = fmaf(p, k, -0.284496736f);
  p = fmaf(p, k, 0.254829592f);
  p = p * k;
  float e = __expf(-s * s);
  float erf_s = copysignf(fmaf(-p, e, 1.0f), s);
  return 0.5f * x * (1.0f + erf_s);
}

// ---------------------------------------------------------------------------
// Pre-kernel: conv(3x5)+bias+gelu -> x2 bf16; out init = ifeats + b2
// (so the split-K gemm can atomically accumulate); w2 fp32->bf16 cast.
// ---------------------------------------------------------------------------
__global__ __launch_bounds__(256) void pre_kernel(
    const float* __restrict__ ifeats, const float* __restrict__ tn,
    const float* __restrict__ ta, const float* __restrict__ cw,
    const float* __restrict__ cb, const float* __restrict__ w2,
    const float* __restrict__ b2, u16* __restrict__ x2,
    u16* __restrict__ w2b, float* __restrict__ out) {
  const int b = blockIdx.x;
  const int t = threadIdx.x;
  if (b < NROWS) {
    __shared__ float si[DIMD], sn[DIMD], sa[DIMD];
    float4 fi = ((const float4*)(ifeats + (size_t)b * DIMD))[t];
    ((float4*)si)[t] = fi;
    ((float4*)sn)[t] = ((const float4*)tn)[t];
    ((float4*)sa)[t] = ((const float4*)ta)[t];
    // out init = ifeats + b2 (this thread's own 4 elements; no barrier needed)
    float4 fb = ((const float4*)b2)[t];
    float4 fo = {fi.x + fb.x, fi.y + fb.y, fi.z + fb.z, fi.w + fb.w};
    ((float4*)(out + (size_t)b * DIMD))[t] = fo;
    __syncthreads();
    const int c = t >> 7;
    const int w0 = (t & 127) << 3;
    float cwn[5], cwa[5], cwi[5];
#pragma unroll
    for (int k = 0; k < 5; ++k) {
      cwn[k] = cw[c * 15 + k];
      cwa[k] = cw[c * 15 + 5 + k];
      cwi[k] = cw[c * 15 + 10 + k];
    }
    const float bias = cb[c];
    float wn[12], wa[12], wi[12];
#pragma unroll
    for (int j = 0; j < 12; ++j) {
      int wp = w0 - 2 + j;
      bool ok = (wp >= 0) && (wp < DIMD);
      wn[j] = ok ? sn[wp] : 0.f;
      wa[j] = ok ? sa[wp] : 0.f;
      wi[j] = ok ? si[wp] : 0.f;
    }
    union { u16 o[8]; uint4 u; } pk;
#pragma unroll
    for (int s = 0; s < 8; ++s) {
      float x = bias;
#pragma unroll
      for (int k = 0; k < 5; ++k) {
        x = fmaf(cwn[k], wn[s + k], x);
        x = fmaf(cwa[k], wa[s + k], x);
        x = fmaf(cwi[k], wi[s + k], x);
      }
      pk.o[s] = f2bf(gelu_exact(x));
    }
    *(uint4*)(x2 + (size_t)b * KDIM + c * DIMD + w0) = pk.u;
  } else {
    const int t2 = (b - NROWS) * 256 + t;
    const float4* p = (const float4*)(w2 + (size_t)t2 * 8);
    float4 a = p[0], bb = p[1];
    union { u16 o[8]; uint4 v; } pk;
    pk.o[0] = f2bf(a.x);  pk.o[1] = f2bf(a.y);  pk.o[2] = f2bf(a.z);  pk.o[3] = f2bf(a.w);
    pk.o[4] = f2bf(bb.x); pk.o[5] = f2bf(bb.y); pk.o[6] = f2bf(bb.z); pk.o[7] = f2bf(bb.w);
    *(uint4*)(w2b + (size_t)t2 * 8) = pk.v;
  }
}

// ---------------------------------------------------------------------------
// Split-K GEMM: out[i][j] += sum_{k in half} x2[i][k] * w2b[j][k]
// 1024 blocks = 512 tiles (128x128) x 2 K-halves -> 4 independent blocks/CU
// (m97's winning phase-mixing config; R3 showed block-lockstep at 2/CU is the
// stall). 4 waves x (64x64) -> 16 MFMA : 8 ds_read per BK=32. BK=32 dbuf
// (32 KB LDS), async prefetch after each barrier. Pair-XOR swizzle
// (chunk ^ ((row>>1)&3), applied on the global side) -> 2 lanes/bank (free).
// Both K-halves of a tile land on the same XCD -> atomics stay L2-resident.
// ---------------------------------------------------------------------------
__device__ __forceinline__ void gl_lds16(const u16* g, u16* l) {
  __builtin_amdgcn_global_load_lds(
      (__attribute__((address_space(1))) void*)g,
      (__attribute__((address_space(3))) void*)l, 16, 0, 0);
}

#define BK 32   // u16 per row per buffer
#define KHALF 1024

__global__ __launch_bounds__(256, 4) void gemm_bt(
    const u16* __restrict__ A,      // x2 bf16 [8192, 2048]
    const u16* __restrict__ B,      // w2 bf16 [1024, 2048]
    float* __restrict__ out) {
  constexpr int K = KDIM;
  __shared__ __align__(16) u16 sA[2][128 * BK];  // 8 KB per buf
  __shared__ __align__(16) u16 sB[2][128 * BK];

  const int tid = threadIdx.x;
  const int wv = tid >> 6;         // wave 0..3
  const int lane = tid & 63;
  // id -> (xcd strip, tile, K-half); halves of a tile share an XCD.
  const int id = blockIdx.x;       // 0..1023
  const int xcd = id & 7;
  const int s_ = id >> 3;          // 0..127
  const int kh = s_ & 1;
  const int t_ = s_ >> 1;          // 0..63
  const int i0 = (xcd * 8 + (t_ >> 3)) * 128;
  const int j0 = (t_ & 7) * 128;
  const int kbase = kh * KHALF;

  const int wm = (wv & 1) * 64;    // wave tile 64x64
  const int wn = (wv >> 1) * 64;
  const int quad = lane >> 4;
  const int r16 = lane & 15;
  // frag read: LDS pos holds global chunk pos^((row>>1)&3)
  const int poff = ((quad ^ ((r16 >> 1) & 3)) << 3);  // u16 offset in row

  // staging: per wave 32 rows of A + 32 of B per buffer; 16 rows per issue.
  // lane -> row = lane>>2, global chunk g = (lane&3) ^ ((lane>>3)&3).
  const int srow = lane >> 2;                  // 0..15
  const int g = (lane & 3) ^ ((lane >> 3) & 3);
  const u16* gA[2];
  const u16* gB[2];
#pragma unroll
  for (int i = 0; i < 2; ++i) {
    int r = wv * 32 + i * 16 + srow;
    gA[i] = A + (size_t)(i0 + r) * K + kbase + g * 8;
    gB[i] = B + (size_t)(j0 + r) * K + kbase + g * 8;
  }

  const f32x4 vzero = {0.f, 0.f, 0.f, 0.f};
  f32x4 acc[4][4];
#pragma unroll
  for (int a = 0; a < 4; ++a)
#pragma unroll
    for (int b = 0; b < 4; ++b) acc[a][b] = vzero;

  auto stage = [&](int buf, int koff) {  // koff relative to kbase
#pragma unroll
    for (int i = 0; i < 2; ++i) {
      gl_lds16(gA[i] + koff, &sA[buf][(wv * 32 + i * 16) * BK]);
      gl_lds16(gB[i] + koff, &sB[buf][(wv * 32 + i * 16) * BK]);
    }
  };

  auto compute = [&](int buf) {
    bf16x8 av[4], bv[4];
#pragma unroll
    for (int mt = 0; mt < 4; ++mt)
      av[mt] = *(const bf16x8*)&sA[buf][(wm + mt * 16 + r16) * BK + poff];
#pragma unroll
    for (int nt = 0; nt < 4; ++nt)
      bv[nt] = *(const bf16x8*)&sB[buf][(wn + nt * 16 + r16) * BK + poff];
#pragma unroll
    for (int mt = 0; mt < 4; ++mt)
#pragma unroll
      for (int nt = 0; nt < 4; ++nt)
        acc[mt][nt] = __builtin_amdgcn_mfma_f32_16x16x32_bf16(av[mt], bv[nt], acc[mt][nt], 0, 0, 0);
  };

  stage(0, 0);
  for (int k0 = 0; k0 < KHALF; k0 += 2 * BK) {
    __syncthreads();                       // drains buf0 loads; buf1 free
    if (k0 + BK < KHALF) stage(1, k0 + BK);
    compute(0);
    __syncthreads();                       // drains buf1 loads (aged 1 phase)
    if (k0 + 2 * BK < KHALF) stage(0, k0 + 2 * BK);
    compute(1);
  }

  // epilogue: C/D layout col=lane&15, row=quad*4+reg; accumulate via HW f32
  // atomics into out (pre-initialized to ifeats + b2).
#pragma unroll
  for (int nt = 0; nt < 4; ++nt) {
    int col = j0 + wn + nt * 16 + r16;
#pragma unroll
    for (int mt = 0; mt < 4; ++mt) {
      int rbase = i0 + wm + mt * 16 + quad * 4;
#pragma unroll
      for (int r = 0; r < 4; ++r) {
        unsafeAtomicAdd(&out[(size_t)(rbase + r) * DIMD + col], acc[mt][nt][r]);
      }
    }
  }
}

// ---------------------------------------------------------------------------
extern "C" void kernel_launch(void* const* d_in, const int* in_sizes, int n_in,
                              void* d_out, int out_size, void* d_ws, size_t ws_size,
                              hipStream_t stream) {
  const float* ifeats = (const float*)d_in[0];
  const float* tn     = (const float*)d_in[1];
  const float* ta     = (const float*)d_in[2];
  const float* cw     = (const float*)d_in[3];
  const float* cb     = (const float*)d_in[4];
  const float* w2     = (const float*)d_in[5];
  const float* b2     = (const float*)d_in[6];
  float* out = (float*)d_out;

  // ws: [0, 4MB) w2 bf16 | [4MB, 36MB) x2 bf16
  u16* w2b = (u16*)d_ws;
  u16* x2  = (u16*)((char*)d_ws + (size_t)DIMD * KDIM * 2);

  pre_kernel<<<NROWS + (DIMD * KDIM / 8) / 256, 256, 0, stream>>>(
      ifeats, tn, ta, cw, cb, w2, b2, x2, w2b, out);
  gemm_bt<<<1024, 256, 0, stream>>>(x2, w2b, out);
}

// Round 5
// 163.082 us; speedup vs baseline: 1.2111x; 1.2111x over previous
//
#include <hip/hip_runtime.h>
#include <cstdint>

#define DIMD 1024
#define NROWS 8192
#define KDIM 2048   // 2*DIM

typedef unsigned short u16;
typedef __bf16 bf16x8 __attribute__((ext_vector_type(8)));
typedef float f32x4 __attribute__((ext_vector_type(4)));

__device__ __forceinline__ u16 f2bf(float f) {
  unsigned u = __builtin_bit_cast(unsigned, f);
  return (u16)((u + 0x7FFFu + ((u >> 16) & 1u)) >> 16);  // RNE
}

// Branch-free exact-enough GELU (A&S 7.1.26 erf, |err| <= 1.5e-7).
__device__ __forceinline__ float gelu_exact(float x) {
  float s = 0.70710678118654752f * x;
  float a = fabsf(s);
  float k = __fdividef(1.0f, fmaf(0.3275911f, a, 1.0f));
  float p = 1.061405429f;
  p = fmaf(p, k, -1.453152027f);
  p = fmaf(p, k, 1.421413741f);
  p = fmaf(p, k, -0.284496736f);
  p = fmaf(p, k, 0.254829592f);
  p = p * k;
  float e = __expf(-s * s);
  float erf_s = copysignf(fmaf(-p, e, 1.0f), s);
  return 0.5f * x * (1.0f + erf_s);
}

// ---------------------------------------------------------------------------
// Pre-kernel: conv(3x5)+bias+gelu -> x2 bf16; w2 fp32->bf16 cast.
// ---------------------------------------------------------------------------
__global__ __launch_bounds__(256) void pre_kernel(
    const float* __restrict__ ifeats, const float* __restrict__ tn,
    const float* __restrict__ ta, const float* __restrict__ cw,
    const float* __restrict__ cb, const float* __restrict__ w2,
    u16* __restrict__ x2, u16* __restrict__ w2b) {
  const int b = blockIdx.x;
  const int t = threadIdx.x;
  if (b < NROWS) {
    __shared__ float si[DIMD], sn[DIMD], sa[DIMD];
    ((float4*)si)[t] = ((const float4*)(ifeats + (size_t)b * DIMD))[t];
    ((float4*)sn)[t] = ((const float4*)tn)[t];
    ((float4*)sa)[t] = ((const float4*)ta)[t];
    __syncthreads();
    const int c = t >> 7;
    const int w0 = (t & 127) << 3;
    float cwn[5], cwa[5], cwi[5];
#pragma unroll
    for (int k = 0; k < 5; ++k) {
      cwn[k] = cw[c * 15 + k];
      cwa[k] = cw[c * 15 + 5 + k];
      cwi[k] = cw[c * 15 + 10 + k];
    }
    const float bias = cb[c];
    float wn[12], wa[12], wi[12];
#pragma unroll
    for (int j = 0; j < 12; ++j) {
      int wp = w0 - 2 + j;
      bool ok = (wp >= 0) && (wp < DIMD);
      wn[j] = ok ? sn[wp] : 0.f;
      wa[j] = ok ? sa[wp] : 0.f;
      wi[j] = ok ? si[wp] : 0.f;
    }
    union { u16 o[8]; uint4 u; } pk;
#pragma unroll
    for (int s = 0; s < 8; ++s) {
      float x = bias;
#pragma unroll
      for (int k = 0; k < 5; ++k) {
        x = fmaf(cwn[k], wn[s + k], x);
        x = fmaf(cwa[k], wa[s + k], x);
        x = fmaf(cwi[k], wi[s + k], x);
      }
      pk.o[s] = f2bf(gelu_exact(x));
    }
    *(uint4*)(x2 + (size_t)b * KDIM + c * DIMD + w0) = pk.u;
  } else {
    const int t2 = (b - NROWS) * 256 + t;
    const float4* p = (const float4*)(w2 + (size_t)t2 * 8);
    float4 a = p[0], bb = p[1];
    union { u16 o[8]; uint4 v; } pk;
    pk.o[0] = f2bf(a.x);  pk.o[1] = f2bf(a.y);  pk.o[2] = f2bf(a.z);  pk.o[3] = f2bf(a.w);
    pk.o[4] = f2bf(bb.x); pk.o[5] = f2bf(bb.y); pk.o[6] = f2bf(bb.z); pk.o[7] = f2bf(bb.w);
    *(uint4*)(w2b + (size_t)t2 * 8) = pk.v;
  }
}

// ---------------------------------------------------------------------------
// GEMM: out[i][j] = ifeats[i][j] + b2[j] + sum_k x2[i][k] * w2b[j][k]
// 128x128 tile, 512 thr = 8 waves, ALL with 64x64 wave tiles via in-block
// K-split: waves 0-3 eat k[0,32) of each BK=64 stage, waves 4-7 eat k[32,64),
// private partials combined once at the end through LDS (no global atomics —
// R4 showed those cost 2x). Per wave-stage 8 ds_read_b128 : 16 MFMA (m97
// ratio) at 16 waves/CU — cuts the LDS pipe load that bounded R3 (78%->~57%).
// BK=64 dbuf, async prefetch after each barrier, XOR swizzle (0 conflicts).
// ---------------------------------------------------------------------------
__device__ __forceinline__ void gl_lds16(const u16* g, u16* l) {
  __builtin_amdgcn_global_load_lds(
      (__attribute__((address_space(1))) void*)g,
      (__attribute__((address_space(3))) void*)l, 16, 0, 0);
}

#define BK 64  // u16 per row per stage

__global__ __launch_bounds__(512, 4) void gemm_bt(
    const u16* __restrict__ A,      // x2 bf16 [8192, 2048]
    const u16* __restrict__ B,      // w2 bf16 [1024, 2048]
    const float* __restrict__ ifeats,
    const float* __restrict__ b2,
    float* __restrict__ out) {
  constexpr int K = KDIM;
  // smem[0..1] = A dbuf, smem[2..3] = B dbuf; whole 64 KB doubles as the
  // f32 partial-exchange scratch in the epilogue.
  __shared__ __align__(16) u16 smem[4][128 * BK];

  const int tid = threadIdx.x;
  const int wv = tid >> 6;         // 0..7
  const int lane = tid & 63;
  const int kgrp = wv >> 2;        // 0: k[0,32) of stage, 1: k[32,64)
  const int wq = wv & 3;           // quadrant of the 128x128 tile
  const int wm = (wq & 1) * 64;
  const int wn = (wq >> 1) * 64;
  const int quad = lane >> 4;
  const int r16 = lane & 15;
  const int sw = r16 & 7;
  const int poff = (((kgrp * 4 + quad) ^ sw) << 3);  // u16 offset in row

  // XCD-aware swizzle (kept from R3: FETCH 150->50 MB)
  const int id = blockIdx.x;       // 0..511
  const int xcd = id & 7;
  const int s_ = id >> 3;          // 0..63
  const int i0 = (xcd * 8 + (s_ >> 3)) * 128;
  const int j0 = (s_ & 7) * 128;

  // staging: per wave 16 A rows + 16 B rows per stage; 8 rows per issue,
  // global 16B chunk (lane&7)^(row&7) -> LDS pos holds chunk^row (0-conflict).
  const int srow = lane >> 3;                 // 0..7
  const int schunk = (lane & 7) ^ srow;
  const u16* gA[2];
  const u16* gB[2];
#pragma unroll
  for (int i = 0; i < 2; ++i) {
    int r = wv * 16 + i * 8 + srow;
    gA[i] = A + (size_t)(i0 + r) * K + schunk * 8;
    gB[i] = B + (size_t)(j0 + r) * K + schunk * 8;
  }

  const f32x4 vzero = {0.f, 0.f, 0.f, 0.f};
  f32x4 acc[4][4];
#pragma unroll
  for (int a = 0; a < 4; ++a)
#pragma unroll
    for (int b = 0; b < 4; ++b) acc[a][b] = vzero;

  auto stage = [&](int buf, int k0) {
#pragma unroll
    for (int i = 0; i < 2; ++i) {
      gl_lds16(gA[i] + k0, &smem[buf][(wv * 16 + i * 8) * BK]);
      gl_lds16(gB[i] + k0, &smem[2 + buf][(wv * 16 + i * 8) * BK]);
    }
  };

  auto compute = [&](int buf) {
    bf16x8 av[4], bv[4];
#pragma unroll
    for (int mt = 0; mt < 4; ++mt)
      av[mt] = *(const bf16x8*)&smem[buf][(wm + mt * 16 + r16) * BK + poff];
#pragma unroll
    for (int nt = 0; nt < 4; ++nt)
      bv[nt] = *(const bf16x8*)&smem[2 + buf][(wn + nt * 16 + r16) * BK + poff];
#pragma unroll
    for (int mt = 0; mt < 4; ++mt)
#pragma unroll
      for (int nt = 0; nt < 4; ++nt)
        acc[mt][nt] = __builtin_amdgcn_mfma_f32_16x16x32_bf16(av[mt], bv[nt], acc[mt][nt], 0, 0, 0);
  };

  stage(0, 0);
  for (int k0 = 0; k0 < K; k0 += 2 * BK) {
    __syncthreads();                    // buf0 staged; buf1 free
    if (k0 + BK < K) stage(1, k0 + BK); // async prefetch
    compute(0);
    __syncthreads();                    // buf1 staged (aged one phase)
    if (k0 + 2 * BK < K) stage(0, k0 + 2 * BK);
    compute(1);
  }

  // ---- combine the two K-halves through LDS scratch (64 KB, reuses smem).
  // XOR swizzle on the M-subindex -> 2 lanes/bank (free).
  __syncthreads();                      // all frag reads done; smem reusable
  float* scr = (float*)smem;
  if (kgrp == 1) {
#pragma unroll
    for (int nt = 0; nt < 4; ++nt)
#pragma unroll
      for (int mt = 0; mt < 4; ++mt) {
        int idx = wq * 4096 + (nt * 16 + r16) * 64 + (((mt * 4 + quad) ^ r16) << 2);
        *(f32x4*)&scr[idx] = acc[mt][nt];
      }
  }
  __syncthreads();
  if (kgrp == 0) {
#pragma unroll
    for (int nt = 0; nt < 4; ++nt) {
      int col = j0 + wn + nt * 16 + r16;
      float bias = b2[col];
#pragma unroll
      for (int mt = 0; mt < 4; ++mt) {
        int idx = wq * 4096 + (nt * 16 + r16) * 64 + (((mt * 4 + quad) ^ r16) << 2);
        f32x4 part = *(const f32x4*)&scr[idx];
        int rbase = i0 + wm + mt * 16 + quad * 4;
#pragma unroll
        for (int r = 0; r < 4; ++r) {
          size_t oix = (size_t)(rbase + r) * DIMD + col;
          out[oix] = ifeats[oix] + bias + acc[mt][nt][r] + part[r];
        }
      }
    }
  }
}

// ---------------------------------------------------------------------------
extern "C" void kernel_launch(void* const* d_in, const int* in_sizes, int n_in,
                              void* d_out, int out_size, void* d_ws, size_t ws_size,
                              hipStream_t stream) {
  const float* ifeats = (const float*)d_in[0];
  const float* tn     = (const float*)d_in[1];
  const float* ta     = (const float*)d_in[2];
  const float* cw     = (const float*)d_in[3];
  const float* cb     = (const float*)d_in[4];
  const float* w2     = (const float*)d_in[5];
  const float* b2     = (const float*)d_in[6];
  float* out = (float*)d_out;

  // ws: [0, 4MB) w2 bf16 | [4MB, 36MB) x2 bf16
  u16* w2b = (u16*)d_ws;
  u16* x2  = (u16*)((char*)d_ws + (size_t)DIMD * KDIM * 2);

  pre_kernel<<<NROWS + (DIMD * KDIM / 8) / 256, 256, 0, stream>>>(
      ifeats, tn, ta, cw, cb, w2, x2, w2b);
  gemm_bt<<<512, 512, 0, stream>>>(x2, w2b, ifeats, b2, out);
}